// Round 6
// baseline (516.229 us; speedup 1.0000x reference)
//
#include <hip/hip_runtime.h>
#include <hip/hip_bf16.h>

// ---------------------------------------------------------------------------
// ConvTokenEmbedder: char-CNN -> 2x highway -> projection
// R13 = R12 with the dirty-flush interference removed:
//     1) All large producer stores are NONTEMPORAL (cvt w0b/w1b/pwb 80 MB,
//        conv h 16 MB, gemm epilogue h2/h, proj out) -> no dirty-L2 flush
//        storm at kernel boundaries landing on the next GEMM's reads.
//        Theory: gemm code was byte-identical R10->R12 yet achieved fetch
//        BW collapsed 1148->665->396 GB/s tracking how close the big dirty
//        writers ran before it.
//     2) Launch order and gemm 1D XCD swizzle reverted to R10 exactly
//        (empirically best gemm: 88.5 us x5 samples).
//     conv_all / gemm K-loop byte-identical to R12.
// ---------------------------------------------------------------------------

#define NTOK 4096
#define NF   2048
#define KDIM 2048
#define HID  4096
#define PDIM 512

typedef __attribute__((ext_vector_type(4))) float floatx4;
typedef __attribute__((ext_vector_type(8))) short shortx8;

__device__ inline void async_copy16(const void* g, void* l) {
  __builtin_amdgcn_global_load_lds(
      (const __attribute__((address_space(1))) void*)(uintptr_t)g,
      (__attribute__((address_space(3))) void*)(uint32_t)(uintptr_t)l,
      16, 0, 0);
}

__device__ inline void bar() {
  __builtin_amdgcn_sched_barrier(0);
  __builtin_amdgcn_s_barrier();
  __builtin_amdgcn_sched_barrier(0);
}

#define WAITCNT_VM(N)                                  \
  do {                                                 \
    __builtin_amdgcn_sched_barrier(0);                 \
    asm volatile("s_waitcnt vmcnt(" #N ")");           \
    __builtin_amdgcn_sched_barrier(0);                 \
  } while (0)

__device__ inline void st_bf16_nt(__hip_bfloat16* p, float v) {
  union { __hip_bfloat16 b; short s; } cv;
  cv.b = __float2bfloat16(v);
  __builtin_nontemporal_store(cv.s, (short*)p);
}

// ---------------------------------------------------------------------------
// Vectorized fp32 -> bf16 (8 elems/thread), nontemporal output.
__global__ __launch_bounds__(256) void cvt8_kernel(
    const float* __restrict__ s, __hip_bfloat16* __restrict__ d, int n8) {
  int i = blockIdx.x * 256 + threadIdx.x;
  if (i < n8) {
    floatx4 v0 = *(const floatx4*)(s + (size_t)i * 8);
    floatx4 v1 = *(const floatx4*)(s + (size_t)i * 8 + 4);
    union { shortx8 v; __hip_bfloat16 h[8]; } u;
#pragma unroll
    for (int t = 0; t < 4; ++t) u.h[t] = __float2bfloat16(v0[t]);
#pragma unroll
    for (int t = 0; t < 4; ++t) u.h[4 + t] = __float2bfloat16(v1[t]);
    __builtin_nontemporal_store(u.v, (shortx8*)(d + (size_t)i * 8));
  }
}

// Highway weight cvt with nl/gate row interleave: dst row r = src row
// (r>>1) + (r&1)*2048. So cols 2j/2j+1 of p' are (nl_j, gate_j).
__global__ __launch_bounds__(256) void cvt_hw8(
    const float* __restrict__ s, __hip_bfloat16* __restrict__ d) {
  int i = blockIdx.x * 256 + threadIdx.x;  // over 4096*2048/8
  int r = i >> 8;             // 256 threads per 2048-wide row
  int kb = (i & 255) * 8;
  int sr = (r >> 1) + (r & 1) * 2048;
  const float* src = s + (size_t)sr * 2048 + kb;
  floatx4 v0 = *(const floatx4*)(src);
  floatx4 v1 = *(const floatx4*)(src + 4);
  union { shortx8 v; __hip_bfloat16 h[8]; } u;
#pragma unroll
  for (int t = 0; t < 4; ++t) u.h[t] = __float2bfloat16(v0[t]);
#pragma unroll
  for (int t = 0; t < 4; ++t) u.h[4 + t] = __float2bfloat16(v1[t]);
  __builtin_nontemporal_store(u.v, (shortx8*)(d + (size_t)r * 2048 + kb));
}

// ---------------------------------------------------------------------------
// Conv weight prep: Wb[ch][kp], kp = k*16+d, K padded to 128 (zeros k>=w).
// Plus bias pack [2048] and bf16 emb table [262*16]. (Outputs are small and
// read by conv next -> keep CACHED stores here.)
// ---------------------------------------------------------------------------
__global__ __launch_bounds__(256) void conv_wprep(
    const float* __restrict__ w0, const float* __restrict__ w1,
    const float* __restrict__ w2, const float* __restrict__ w3,
    const float* __restrict__ w4, const float* __restrict__ w5,
    const float* __restrict__ w6,
    const float* __restrict__ b0, const float* __restrict__ b1,
    const float* __restrict__ b2, const float* __restrict__ b3,
    const float* __restrict__ b4, const float* __restrict__ b5,
    const float* __restrict__ b6, const float* __restrict__ emb,
    __hip_bfloat16* __restrict__ Wb, float* __restrict__ Bc,
    __hip_bfloat16* __restrict__ embb) {
  int idx = blockIdx.x * 256 + threadIdx.x;
  const int start[7] = {0, 32, 64, 128, 256, 512, 1024};
  const float* ws[7] = {w0, w1, w2, w3, w4, w5, w6};
  const float* bs[7] = {b0, b1, b2, b3, b4, b5, b6};
  if (idx < 262144) {
    int ch = idx >> 7, kp = idx & 127;
    int f = (ch >= 32) + (ch >= 64) + (ch >= 128) + (ch >= 256) +
            (ch >= 512) + (ch >= 1024);
    int w = f + 1, lc = ch - start[f];
    int d = kp & 15, k = kp >> 4;
    float v = (k < w) ? ws[f][((size_t)lc * 16 + d) * w + k] : 0.f;
    Wb[idx] = __float2bfloat16(v);
  } else if (idx < 262144 + 2048) {
    int ch = idx - 262144;
    int f = (ch >= 32) + (ch >= 64) + (ch >= 128) + (ch >= 256) +
            (ch >= 512) + (ch >= 1024);
    Bc[ch] = bs[f][ch - start[f]];
  } else if (idx < 262144 + 2048 + 4192) {
    int e = idx - 262144 - 2048;
    embb[e] = __float2bfloat16(emb[e]);
  }
}

// ---------------------------------------------------------------------------
// Conv, LDS-free: each wave handles 64 channels x 8 tokens (one at a time).
// A-fragment built by direct gather: c = shfl(char row reg, t'), then a
// 16B load from the L1-resident embb table, zero-predicated for t' >= 50.
// W register-resident; no LDS, no barriers. h store NONTEMPORAL.
// ---------------------------------------------------------------------------
template <int NKT, int NT>
__device__ __forceinline__ void conv_body(
    const int* __restrict__ chars, const __hip_bfloat16* __restrict__ embb,
    const __hip_bfloat16* __restrict__ Wb, const float* __restrict__ bias,
    __hip_bfloat16* __restrict__ h, int chb, int tokbase) {
  int tid = threadIdx.x, wave = tid >> 6, lane = tid & 63;
  int frow = lane & 15, q = lane >> 4;

  shortx8 wreg[NKT][4];
#pragma unroll
  for (int kt = 0; kt < NKT; ++kt)
#pragma unroll
    for (int j = 0; j < 4; ++j)
      wreg[kt][j] = *(const shortx8*)(
          Wb + (size_t)(chb + j * 16 + frow) * 128 + kt * 32 + q * 8);

  float blane = bias[chb + lane];
  int Tvj[4];
#pragma unroll
  for (int j = 0; j < 4; ++j) {
    int ch = chb + j * 16 + frow;
    int w = 1 + (ch >= 32) + (ch >= 64) + (ch >= 128) + (ch >= 256) +
            (ch >= 512) + (ch >= 1024);
    Tvj[j] = 51 - w;
  }

  const floatx4 zero = {0.f, 0.f, 0.f, 0.f};
  int kkb = q >> 1, d0 = (q & 1) * 8;

#pragma unroll 1
  for (int g = 0; g < 8; ++g) {
    int tok = tokbase + g * 4 + wave;
    int crow = (lane < 50) ? chars[(size_t)tok * 50 + lane] : 0;

    floatx4 acc[NT][4];
#pragma unroll
    for (int kt = 0; kt < NKT; ++kt) {
      int kk = kt * 2 + kkb;
      shortx8 xf[NT];
#pragma unroll
      for (int i = 0; i < NT; ++i) {
        int tp = i * 16 + frow + kk;
        int c = __shfl(crow, tp & 63);
        shortx8 xv = {0, 0, 0, 0, 0, 0, 0, 0};
        if (tp < 50) xv = *(const shortx8*)(embb + c * 16 + d0);
        xf[i] = xv;
      }
#pragma unroll
      for (int i = 0; i < NT; ++i)
#pragma unroll
        for (int j = 0; j < 4; ++j) {
          if (kt == 0)
            acc[i][j] = __builtin_amdgcn_mfma_f32_16x16x32_bf16(
                xf[i], wreg[0][j], zero, 0, 0, 0);
          else
            acc[i][j] = __builtin_amdgcn_mfma_f32_16x16x32_bf16(
                xf[i], wreg[kt][j], acc[i][j], 0, 0, 0);
        }
    }

    float vj[4];
#pragma unroll
    for (int j = 0; j < 4; ++j) {
      float v = -1e30f;
#pragma unroll
      for (int i = 0; i < NT; ++i) {
#pragma unroll
        for (int r = 0; r < 4; ++r) {
          if (i < 2) {  // t <= 31 < Tv_min=44: always valid
            v = fmaxf(v, acc[i][j][r]);
          } else {
            int t = i * 16 + q * 4 + r;
            if (t < Tvj[j]) v = fmaxf(v, acc[i][j][r]);
          }
        }
      }
      v = fmaxf(v, __shfl_xor(v, 16));
      v = fmaxf(v, __shfl_xor(v, 32));
      vj[j] = v;
    }
    float r0 = (q & 2) ? vj[2] : vj[0];
    float r1 = (q & 2) ? vj[3] : vj[1];
    float rv = (q & 1) ? r1 : r0;
    st_bf16_nt(h + (size_t)tok * NF + chb + lane,
               fmaxf(rv + blane, 0.f));
  }
}

__global__ __launch_bounds__(256) void conv_all(
    const int* __restrict__ chars, const __hip_bfloat16* __restrict__ embb,
    const __hip_bfloat16* __restrict__ Wb, const float* __restrict__ bias,
    __hip_bfloat16* __restrict__ h) {
  int by = blockIdx.y;
  int chb = by * 64;
  int tokbase = blockIdx.x * 32;
  if (by == 0)
    conv_body<1, 4>(chars, embb, Wb, bias, h, chb, tokbase);
  else if (by < 4)
    conv_body<2, 3>(chars, embb, Wb, bias, h, chb, tokbase);
  else if (by < 16)
    conv_body<3, 3>(chars, embb, Wb, bias, h, chb, tokbase);
  else
    conv_body<4, 3>(chars, embb, Wb, bias, h, chb, tokbase);
}

// ---------------------------------------------------------------------------
// Highway-fused GEMM, 256x256 tile, deep-pipelined, 2 barriers per K-tile.
// R13: 1D XCD swizzle restored to R10's exact form; epilogue Hdst store
// NONTEMPORAL. K-loop byte-identical to R10.
// ---------------------------------------------------------------------------
__global__ __launch_bounds__(512, 2) void gemm_hw8(
    const __hip_bfloat16* __restrict__ A, const __hip_bfloat16* __restrict__ B,
    const float* __restrict__ hwb, __hip_bfloat16* __restrict__ Hdst) {
  __shared__ __align__(16) __hip_bfloat16 As[2 * 256 * 64];
  __shared__ __align__(16) __hip_bfloat16 Bs[2 * 256 * 64];
  int tid = threadIdx.x;
  int wave = tid >> 6, lane = tid & 63;
  int wr = wave >> 2, wc = wave & 3;     // 2 x 4 wave grid
  int sr8 = lane >> 3, sc8 = lane & 7;   // staging row-in-seg / chunk slot
  int frow = lane & 15, q = lane >> 4;

  // Bijective 1D XCD swizzle (R10): XCD x gets bn {2x,2x+1}.
  int wg = blockIdx.x;
  int swz = (wg & 7) * 32 + (wg >> 3);
  int bm = swz & 15;   // w tile (N dim)
  int bn = swz >> 4;   // token tile (M dim)

  const __hip_bfloat16* Ab = A + (size_t)bn * 256 * KDIM;
  const __hip_bfloat16* Bb = B + (size_t)bm * 256 * KDIM;

  floatx4 acc[8][4];
  const floatx4 zero = {0.f, 0.f, 0.f, 0.f};
#pragma unroll
  for (int i = 0; i < 8; ++i)
#pragma unroll
    for (int j = 0; j < 4; ++j) acc[i][j] = zero;

  auto stage_half = [&](const __hip_bfloat16* gsrc, __hip_bfloat16* lbase,
                        int d, int hf, int kb) {
#pragma unroll
    for (int it = 0; it < 2; ++it) {
      int row = hf * 128 + (wave * 2 + it) * 8;  // segment start row (uniform)
      int r = row + sr8;
      int gc = sc8 ^ sr8;
      async_copy16(gsrc + (size_t)r * KDIM + kb + gc * 8,
                   (char*)lbase + ((size_t)d * 256 + row) * 128);
    }
  };

  auto lda2 = [&](shortx8* dst2, const __hip_bfloat16* Asd, int i0, int s) {
#pragma unroll
    for (int ii = 0; ii < 2; ++ii) {
      int r = wr * 128 + (i0 + ii) * 16 + frow;
      dst2[ii] = *(const shortx8*)(Asd + r * 64 +
                                   (((s * 4 + q) ^ (frow & 7)) << 3));
    }
  };
  auto ldb4 = [&](shortx8* dst4, const __hip_bfloat16* Bsd, int s) {
#pragma unroll
    for (int j = 0; j < 4; ++j) {
      int r = wc * 64 + j * 16 + frow;
      dst4[j] = *(const shortx8*)(Bsd + r * 64 +
                                  (((s * 4 + q) ^ (frow & 7)) << 3));
    }
  };
  auto mma8 = [&](const shortx8* aX, const shortx8* bX, int i0) {
    __builtin_amdgcn_s_setprio(1);
#pragma unroll
    for (int ii = 0; ii < 2; ++ii)
#pragma unroll
      for (int j = 0; j < 4; ++j)
        acc[i0 + ii][j] = __builtin_amdgcn_mfma_f32_16x16x32_bf16(
            aX[ii], bX[j], acc[i0 + ii][j], 0, 0, 0);
    __builtin_amdgcn_s_setprio(0);
  };

  // Prologue: tile 0 fully staged + B(1) in flight.
  stage_half(Ab, As, 0, 0, 0);
  stage_half(Ab, As, 0, 1, 0);
  stage_half(Bb, Bs, 0, 0, 0);
  stage_half(Bb, Bs, 0, 1, 0);
  stage_half(Bb, Bs, 1, 0, 64);
  stage_half(Bb, Bs, 1, 1, 64);
  WAITCNT_VM(4);  // tile 0 done, B(1)'s 4 loads stay in flight
  bar();

  const int NTILE = KDIM / 64;  // 32
#pragma unroll 2
  for (int T = 0; T < NTILE; ++T) {
    int d = T & 1, d1 = d ^ 1;
    const __hip_bfloat16* Asd = As + d * 16384;
    const __hip_bfloat16* Bsd = Bs + d * 16384;
    int kn = (T + 1) * 64;

    shortx8 aU[2], aV[2], b0[4], b1[4];
    // t0
    ldb4(b0, Bsd, 0);
    lda2(aU, Asd, 0, 0);
    if (T + 1 < NTILE) {
      stage_half(Ab, As, d1, 0, kn);
      stage_half(Ab, As, d1, 1, kn);
    }
    lda2(aV, Asd, 2, 0);
    mma8(aU, b0, 0);
    // t1
    lda2(aU, Asd, 4, 0);
    mma8(aV, b0, 2);
    // t2
    lda2(aV, Asd, 6, 0);
    ldb4(b1, Bsd, 1);
    mma8(aU, b0, 4);
    // t3
    lda2(aU, Asd, 0, 1);
    mma8(aV, b0, 6);
    // t4
    lda2(aV, Asd, 2, 1);
    mma8(aU, b1, 0);
    bar();  // all waves' B(T) reads consumed -> B(T+2) stage safe
    // t5
    if (T + 2 < NTILE) stage_half(Bb, Bs, d, 0, kn + 64);
    lda2(aU, Asd, 4, 1);
    mma8(aV, b1, 2);
    // t6
    if (T + 2 < NTILE) stage_half(Bb, Bs, d, 1, kn + 64);
    lda2(aV, Asd, 6, 1);
    mma8(aU, b1, 4);
    // t7
    mma8(aV, b1, 6);
    if (T + 2 < NTILE) {
      WAITCNT_VM(4);  // tile T+1 complete; B(T+2)'s 4 loads in flight
    } else if (T + 1 < NTILE) {
      WAITCNT_VM(0);  // tail drain (no prefetch outstanding after)
    }
    bar();
  }

  // Epilogue: highway gate fuse; nontemporal Hdst store.
  int crow0 = bn * 256 + wr * 128 + q * 4;
  int ccol0 = bm * 256 + wc * 64 + frow;
#pragma unroll
  for (int i = 0; i < 8; ++i)
#pragma unroll
    for (int j = 0; j < 4; ++j) {
      int gcol = ccol0 + j * 16;
      float bb = (gcol & 1) ? hwb[2048 + (gcol >> 1)] : hwb[gcol >> 1];
#pragma unroll
      for (int r = 0; r < 4; ++r) {
        int row = crow0 + i * 16 + r;
        float v = acc[i][j][r] + bb;
        float partner = __shfl_xor(v, 1);
        if (!(lane & 1)) {  // even lane holds nl, partner is gate pre-act
          float gte = 1.f / (1.f + expf(-partner));
          int ch = gcol >> 1;
          float hold = __bfloat162float(A[(size_t)row * 2048 + ch]);
          float hnew = gte * hold + (1.f - gte) * fmaxf(v, 0.f);
          st_bf16_nt(Hdst + (size_t)row * 2048 + ch, hnew);
        }
      }
    }
}

// ---------------------------------------------------------------------------
// Projection GEMM: 32x128 tile (grid 4x128 = 512 blocks, 2/CU), BK=64,
// same XOR swizzle. C fp32 + bias, nontemporal store.
// ---------------------------------------------------------------------------
__global__ __launch_bounds__(256) void gemm_proj(
    const __hip_bfloat16* __restrict__ A, const __hip_bfloat16* __restrict__ B,
    float* __restrict__ C, const float* __restrict__ bias) {
  const int K = KDIM;
  __shared__ __align__(16) __hip_bfloat16 As[32 * 64];
  __shared__ __align__(16) __hip_bfloat16 Bs[128 * 64];
  int tid = threadIdx.x;
  int wave = tid >> 6, lane = tid & 63;
  int wr = wave >> 1, wc = wave & 1;
  int bn = blockIdx.y, bm = blockIdx.x;

  int sr8 = lane >> 3, sc8 = lane & 7;
  int frow = lane & 15, q = lane >> 4;

  floatx4 acc[4];
  floatx4 zero = {0.f, 0.f, 0.f, 0.f};
#pragma unroll
  for (int j = 0; j < 4; ++j) acc[j] = zero;

  const __hip_bfloat16* Ab = A + (size_t)bn * 32 * K;
  const __hip_bfloat16* Bb = B + (size_t)bm * 128 * K;

  for (int kb = 0; kb < K; kb += 64) {
    __syncthreads();
    {
      int r = wave * 8 + sr8;
      int gc = sc8 ^ (r & 7);
      async_copy16(Ab + (size_t)r * K + kb + gc * 8, (char*)As + wave * 1024);
    }
#pragma unroll
    for (int it = 0; it < 4; ++it) {
      int seg = wave * 4 + it;
      int r = seg * 8 + sr8;
      int gc = sc8 ^ (r & 7);
      async_copy16(Bb + (size_t)r * K + kb + gc * 8, (char*)Bs + seg * 1024);
    }
    __syncthreads();

#pragma unroll
    for (int s = 0; s < 2; ++s) {
      shortx8 af, bf[4];
      {
        int r = wr * 16 + frow;
        af = *(const shortx8*)(As + r * 64 + ((s * 4 + q) ^ (r & 7)) * 8);
      }
#pragma unroll
      for (int j = 0; j < 4; ++j) {
        int r = wc * 64 + j * 16 + frow;
        bf[j] = *(const shortx8*)(Bs + r * 64 + ((s * 4 + q) ^ (r & 7)) * 8);
      }
#pragma unroll
      for (int j = 0; j < 4; ++j)
        acc[j] = __builtin_amdgcn_mfma_f32_16x16x32_bf16(af, bf[j], acc[j],
                                                          0, 0, 0);
    }
  }

  int crow0 = bn * 32 + wr * 16 + q * 4;
  int ccol0 = bm * 128 + wc * 64 + frow;
#pragma unroll
  for (int j = 0; j < 4; ++j) {
    int c = ccol0 + j * 16;
#pragma unroll
    for (int r = 0; r < 4; ++r) {
      int row = crow0 + r;
      __builtin_nontemporal_store(acc[j][r] + bias[c],
                                  C + (size_t)row * PDIM + c);
    }
  }
}

// ---------------------------------------------------------------------------
extern "C" void kernel_launch(void* const* d_in, const int* in_sizes, int n_in,
                              void* d_out, int out_size, void* d_ws, size_t ws_size,
                              hipStream_t stream) {
  const int*   chars  = (const int*)d_in[1];
  const float* emb    = (const float*)d_in[2];
  const float* cw[7];
  const float* cb[7];
  for (int i = 0; i < 7; ++i) {
    cw[i] = (const float*)d_in[3 + 2 * i];
    cb[i] = (const float*)d_in[4 + 2 * i];
  }
  const float* hw_w0  = (const float*)d_in[17];
  const float* hw_b0  = (const float*)d_in[18];
  const float* hw_w1  = (const float*)d_in[19];
  const float* hw_b1  = (const float*)d_in[20];
  const float* proj_w = (const float*)d_in[21];
  const float* proj_b = (const float*)d_in[22];
  float* out = (float*)d_out;

  // Workspace (82 MiB):
  //   [0,16)   h   bf16 4096x2048      [16,32) h2  bf16 4096x2048
  //   [32,48)  convWb 512KB + convBc 8KB + embb 8.4KB
  //   [48,64)  w0b  [64,80) w1b  [80,82) pwb
  char* ws = (char*)d_ws;
  __hip_bfloat16* h      = (__hip_bfloat16*)(ws);
  __hip_bfloat16* h2     = (__hip_bfloat16*)(ws + (16ull << 20));
  __hip_bfloat16* convWb = (__hip_bfloat16*)(ws + (32ull << 20));
  float*          convBc = (float*)(ws + (32ull << 20) + 524288);
  __hip_bfloat16* embb   = (__hip_bfloat16*)(ws + (32ull << 20) + 524288 + 8192);
  __hip_bfloat16* w0b    = (__hip_bfloat16*)(ws + (48ull << 20));
  __hip_bfloat16* w1b    = (__hip_bfloat16*)(ws + (64ull << 20));
  __hip_bfloat16* pwb    = (__hip_bfloat16*)(ws + (80ull << 20));

  // R10 order: cvts first (NT stores -> no flush debt), then prep + conv,
  // then the GEMMs.
  cvt_hw8<<<(HID * KDIM / 8) / 256, 256, 0, stream>>>(hw_w0, w0b);
  cvt_hw8<<<(HID * KDIM / 8) / 256, 256, 0, stream>>>(hw_w1, w1b);
  cvt8_kernel<<<(PDIM * KDIM / 8) / 256, 256, 0, stream>>>(proj_w, pwb,
                                                           PDIM * KDIM / 8);
  conv_wprep<<<(262144 + 2048 + 4192 + 255) / 256, 256, 0, stream>>>(
      cw[0], cw[1], cw[2], cw[3], cw[4], cw[5], cw[6],
      cb[0], cb[1], cb[2], cb[3], cb[4], cb[5], cb[6], emb,
      convWb, convBc, embb);

  // Conv: single LDS-free launch over all 2048 channels x 4096 tokens.
  conv_all<<<dim3(128, 32), 256, 0, stream>>>(chars, embb, convWb, convBc, h);

  // 256^2-tile deep-pipelined highway GEMMs: grid 256 (1 block/CU), 512 thr.
  gemm_hw8<<<dim3(256), 512, 0, stream>>>(h, w0b, hw_b0, h2);
  gemm_hw8<<<dim3(256), 512, 0, stream>>>(h2, w1b, hw_b1, h);
  gemm_proj<<<dim3(PDIM / 128, NTOK / 32), 256, 0, stream>>>(h, pwb, out,
                                                             proj_b);
}

// Round 8
// 438.996 us; speedup vs baseline: 1.1759x; 1.1759x over previous
//
#include <hip/hip_runtime.h>
#include <hip/hip_bf16.h>

// ---------------------------------------------------------------------------
// ConvTokenEmbedder: char-CNN -> 2x highway -> projection
// R15 = R14 resubmitted unchanged (R14's bench died to an infra failure —
//     "container failed twice" — with no kernel signal; code re-audited for
//     OOB/hang risk: none found).
//     R14 = R10-exact GEMM/cvt/order + conv rebuilt around a
//     pre-materialized im2col:
//     - conv_xprep: Xg[4096][72][16] bf16, rows 50..71 zero (9 MB, L2-
//       resident per XCD). One gather per (tok,row), done ONCE.
//     - conv_all: A-fragment = single global_load_dwordx4 at constant
//       offset from Xg (no shfl, no cndmask, no per-by re-gather).
//       MFMA / Tvj masking / epilogue / grid byte-identical to R11.
// ---------------------------------------------------------------------------

#define NTOK 4096
#define NF   2048
#define KDIM 2048
#define HID  4096
#define PDIM 512

typedef __attribute__((ext_vector_type(4))) float floatx4;
typedef __attribute__((ext_vector_type(8))) short shortx8;

__device__ inline void async_copy16(const void* g, void* l) {
  __builtin_amdgcn_global_load_lds(
      (const __attribute__((address_space(1))) void*)(uintptr_t)g,
      (__attribute__((address_space(3))) void*)(uint32_t)(uintptr_t)l,
      16, 0, 0);
}

__device__ inline void bar() {
  __builtin_amdgcn_sched_barrier(0);
  __builtin_amdgcn_s_barrier();
  __builtin_amdgcn_sched_barrier(0);
}

#define WAITCNT_VM(N)                                  \
  do {                                                 \
    __builtin_amdgcn_sched_barrier(0);                 \
    asm volatile("s_waitcnt vmcnt(" #N ")");           \
    __builtin_amdgcn_sched_barrier(0);                 \
  } while (0)

// ---------------------------------------------------------------------------
// Vectorized fp32 -> bf16 (8 elems/thread).
__global__ __launch_bounds__(256) void cvt8_kernel(
    const float* __restrict__ s, __hip_bfloat16* __restrict__ d, int n8) {
  int i = blockIdx.x * 256 + threadIdx.x;
  if (i < n8) {
    floatx4 v0 = *(const floatx4*)(s + (size_t)i * 8);
    floatx4 v1 = *(const floatx4*)(s + (size_t)i * 8 + 4);
    union { shortx8 v; __hip_bfloat16 h[8]; } u;
#pragma unroll
    for (int t = 0; t < 4; ++t) u.h[t] = __float2bfloat16(v0[t]);
#pragma unroll
    for (int t = 0; t < 4; ++t) u.h[4 + t] = __float2bfloat16(v1[t]);
    *(shortx8*)(d + (size_t)i * 8) = u.v;
  }
}

// Highway weight cvt with nl/gate row interleave: dst row r = src row
// (r>>1) + (r&1)*2048. So cols 2j/2j+1 of p' are (nl_j, gate_j).
__global__ __launch_bounds__(256) void cvt_hw8(
    const float* __restrict__ s, __hip_bfloat16* __restrict__ d) {
  int i = blockIdx.x * 256 + threadIdx.x;  // over 4096*2048/8
  int r = i >> 8;             // 256 threads per 2048-wide row
  int kb = (i & 255) * 8;
  int sr = (r >> 1) + (r & 1) * 2048;
  const float* src = s + (size_t)sr * 2048 + kb;
  floatx4 v0 = *(const floatx4*)(src);
  floatx4 v1 = *(const floatx4*)(src + 4);
  union { shortx8 v; __hip_bfloat16 h[8]; } u;
#pragma unroll
  for (int t = 0; t < 4; ++t) u.h[t] = __float2bfloat16(v0[t]);
#pragma unroll
  for (int t = 0; t < 4; ++t) u.h[4 + t] = __float2bfloat16(v1[t]);
  *(shortx8*)(d + (size_t)r * 2048 + kb) = u.v;
}

// ---------------------------------------------------------------------------
// Conv weight prep: Wb[ch][kp], kp = k*16+d, K padded to 128 (zeros k>=w).
// Plus bias pack [2048] and bf16 emb table [262*16].
// ---------------------------------------------------------------------------
__global__ __launch_bounds__(256) void conv_wprep(
    const float* __restrict__ w0, const float* __restrict__ w1,
    const float* __restrict__ w2, const float* __restrict__ w3,
    const float* __restrict__ w4, const float* __restrict__ w5,
    const float* __restrict__ w6,
    const float* __restrict__ b0, const float* __restrict__ b1,
    const float* __restrict__ b2, const float* __restrict__ b3,
    const float* __restrict__ b4, const float* __restrict__ b5,
    const float* __restrict__ b6, const float* __restrict__ emb,
    __hip_bfloat16* __restrict__ Wb, float* __restrict__ Bc,
    __hip_bfloat16* __restrict__ embb) {
  int idx = blockIdx.x * 256 + threadIdx.x;
  const int start[7] = {0, 32, 64, 128, 256, 512, 1024};
  const float* ws[7] = {w0, w1, w2, w3, w4, w5, w6};
  const float* bs[7] = {b0, b1, b2, b3, b4, b5, b6};
  if (idx < 262144) {
    int ch = idx >> 7, kp = idx & 127;
    int f = (ch >= 32) + (ch >= 64) + (ch >= 128) + (ch >= 256) +
            (ch >= 512) + (ch >= 1024);
    int w = f + 1, lc = ch - start[f];
    int d = kp & 15, k = kp >> 4;
    float v = (k < w) ? ws[f][((size_t)lc * 16 + d) * w + k] : 0.f;
    Wb[idx] = __float2bfloat16(v);
  } else if (idx < 262144 + 2048) {
    int ch = idx - 262144;
    int f = (ch >= 32) + (ch >= 64) + (ch >= 128) + (ch >= 256) +
            (ch >= 512) + (ch >= 1024);
    Bc[ch] = bs[f][ch - start[f]];
  } else if (idx < 262144 + 2048 + 4192) {
    int e = idx - 262144 - 2048;
    embb[e] = __float2bfloat16(emb[e]);
  }
}

// ---------------------------------------------------------------------------
// im2col pre-materialization: Xg[tok][r][d], r in [0,72), rows >= 50 zero.
// One 32B row per thread, fully coalesced.
// ---------------------------------------------------------------------------
__global__ __launch_bounds__(256) void conv_xprep(
    const int* __restrict__ chars, const __hip_bfloat16* __restrict__ embb,
    __hip_bfloat16* __restrict__ Xg) {
  int idx = blockIdx.x * 256 + threadIdx.x;  // over 4096*72
  if (idx >= NTOK * 72) return;
  int tok = idx / 72, r = idx - tok * 72;
  shortx8 v0 = {0, 0, 0, 0, 0, 0, 0, 0};
  shortx8 v1 = {0, 0, 0, 0, 0, 0, 0, 0};
  if (r < 50) {
    int c = chars[(size_t)tok * 50 + r];
    const shortx8* e = (const shortx8*)(embb + c * 16);
    v0 = e[0];
    v1 = e[1];
  }
  *(shortx8*)(Xg + (size_t)idx * 16) = v0;
  *(shortx8*)(Xg + (size_t)idx * 16 + 8) = v1;
}

// ---------------------------------------------------------------------------
// Conv: A-fragments loaded straight from Xg at constant offsets.
// Each wave: 64 channels x 8 tokens. W register-resident. No LDS/barriers.
// ---------------------------------------------------------------------------
template <int NKT, int NT>
__device__ __forceinline__ void conv_body(
    const __hip_bfloat16* __restrict__ Xg,
    const __hip_bfloat16* __restrict__ Wb, const float* __restrict__ bias,
    __hip_bfloat16* __restrict__ h, int chb, int tokbase) {
  int tid = threadIdx.x, wave = tid >> 6, lane = tid & 63;
  int frow = lane & 15, q = lane >> 4;

  shortx8 wreg[NKT][4];
#pragma unroll
  for (int kt = 0; kt < NKT; ++kt)
#pragma unroll
    for (int j = 0; j < 4; ++j)
      wreg[kt][j] = *(const shortx8*)(
          Wb + (size_t)(chb + j * 16 + frow) * 128 + kt * 32 + q * 8);

  float blane = bias[chb + lane];
  int Tvj[4];
#pragma unroll
  for (int j = 0; j < 4; ++j) {
    int ch = chb + j * 16 + frow;
    int w = 1 + (ch >= 32) + (ch >= 64) + (ch >= 128) + (ch >= 256) +
            (ch >= 512) + (ch >= 1024);
    Tvj[j] = 51 - w;
  }

  const floatx4 zero = {0.f, 0.f, 0.f, 0.f};
  int kkb = q >> 1, d0 = (q & 1) * 8;

#pragma unroll 1
  for (int g = 0; g < 8; ++g) {
    int tok = tokbase + g * 4 + wave;
    // Per-lane base: row (frow + kkb), half d0. (kt,i) offsets are literals.
    const __hip_bfloat16* Xt =
        Xg + ((size_t)tok * 72 + frow + kkb) * 16 + d0;

    floatx4 acc[NT][4];
#pragma unroll
    for (int kt = 0; kt < NKT; ++kt) {
      shortx8 xf[NT];
#pragma unroll
      for (int i = 0; i < NT; ++i)
        xf[i] = *(const shortx8*)(Xt + (size_t)(i * 16 + kt * 2) * 16);
#pragma unroll
      for (int i = 0; i < NT; ++i)
#pragma unroll
        for (int j = 0; j < 4; ++j) {
          if (kt == 0)
            acc[i][j] = __builtin_amdgcn_mfma_f32_16x16x32_bf16(
                xf[i], wreg[0][j], zero, 0, 0, 0);
          else
            acc[i][j] = __builtin_amdgcn_mfma_f32_16x16x32_bf16(
                xf[i], wreg[kt][j], acc[i][j], 0, 0, 0);
        }
    }

    float vj[4];
#pragma unroll
    for (int j = 0; j < 4; ++j) {
      float v = -1e30f;
#pragma unroll
      for (int i = 0; i < NT; ++i) {
#pragma unroll
        for (int r = 0; r < 4; ++r) {
          if (i < 2) {  // t <= 31 < Tv_min=44: always valid
            v = fmaxf(v, acc[i][j][r]);
          } else {
            int t = i * 16 + q * 4 + r;
            if (t < Tvj[j]) v = fmaxf(v, acc[i][j][r]);
          }
        }
      }
      v = fmaxf(v, __shfl_xor(v, 16));
      v = fmaxf(v, __shfl_xor(v, 32));
      vj[j] = v;
    }
    float r0 = (q & 2) ? vj[2] : vj[0];
    float r1 = (q & 2) ? vj[3] : vj[1];
    float rv = (q & 1) ? r1 : r0;
    h[(size_t)tok * NF + chb + lane] =
        __float2bfloat16(fmaxf(rv + blane, 0.f));
  }
}

__global__ __launch_bounds__(256) void conv_all(
    const __hip_bfloat16* __restrict__ Xg,
    const __hip_bfloat16* __restrict__ Wb, const float* __restrict__ bias,
    __hip_bfloat16* __restrict__ h) {
  int by = blockIdx.y;
  int chb = by * 64;
  int tokbase = blockIdx.x * 32;
  if (by == 0)
    conv_body<1, 4>(Xg, Wb, bias, h, chb, tokbase);
  else if (by < 4)
    conv_body<2, 3>(Xg, Wb, bias, h, chb, tokbase);
  else if (by < 16)
    conv_body<3, 3>(Xg, Wb, bias, h, chb, tokbase);
  else
    conv_body<4, 3>(Xg, Wb, bias, h, chb, tokbase);
}

// ---------------------------------------------------------------------------
// Highway-fused GEMM, 256x256 tile, deep-pipelined, 2 barriers per K-tile.
// Byte-identical to R10 (best measured: 88.5 us x5).
// ---------------------------------------------------------------------------
__global__ __launch_bounds__(512, 2) void gemm_hw8(
    const __hip_bfloat16* __restrict__ A, const __hip_bfloat16* __restrict__ B,
    const float* __restrict__ hwb, __hip_bfloat16* __restrict__ Hdst) {
  __shared__ __align__(16) __hip_bfloat16 As[2 * 256 * 64];
  __shared__ __align__(16) __hip_bfloat16 Bs[2 * 256 * 64];
  int tid = threadIdx.x;
  int wave = tid >> 6, lane = tid & 63;
  int wr = wave >> 2, wc = wave & 3;     // 2 x 4 wave grid
  int sr8 = lane >> 3, sc8 = lane & 7;   // staging row-in-seg / chunk slot
  int frow = lane & 15, q = lane >> 4;

  // Bijective 1D XCD swizzle (R10): XCD x gets bn {2x,2x+1}.
  int wg = blockIdx.x;
  int swz = (wg & 7) * 32 + (wg >> 3);
  int bm = swz & 15;   // w tile (N dim)
  int bn = swz >> 4;   // token tile (M dim)

  const __hip_bfloat16* Ab = A + (size_t)bn * 256 * KDIM;
  const __hip_bfloat16* Bb = B + (size_t)bm * 256 * KDIM;

  floatx4 acc[8][4];
  const floatx4 zero = {0.f, 0.f, 0.f, 0.f};
#pragma unroll
  for (int i = 0; i < 8; ++i)
#pragma unroll
    for (int j = 0; j < 4; ++j) acc[i][j] = zero;

  auto stage_half = [&](const __hip_bfloat16* gsrc, __hip_bfloat16* lbase,
                        int d, int hf, int kb) {
#pragma unroll
    for (int it = 0; it < 2; ++it) {
      int row = hf * 128 + (wave * 2 + it) * 8;  // segment start row (uniform)
      int r = row + sr8;
      int gc = sc8 ^ sr8;
      async_copy16(gsrc + (size_t)r * KDIM + kb + gc * 8,
                   (char*)lbase + ((size_t)d * 256 + row) * 128);
    }
  };

  auto lda2 = [&](shortx8* dst2, const __hip_bfloat16* Asd, int i0, int s) {
#pragma unroll
    for (int ii = 0; ii < 2; ++ii) {
      int r = wr * 128 + (i0 + ii) * 16 + frow;
      dst2[ii] = *(const shortx8*)(Asd + r * 64 +
                                   (((s * 4 + q) ^ (frow & 7)) << 3));
    }
  };
  auto ldb4 = [&](shortx8* dst4, const __hip_bfloat16* Bsd, int s) {
#pragma unroll
    for (int j = 0; j < 4; ++j) {
      int r = wc * 64 + j * 16 + frow;
      dst4[j] = *(const shortx8*)(Bsd + r * 64 +
                                  (((s * 4 + q) ^ (frow & 7)) << 3));
    }
  };
  auto mma8 = [&](const shortx8* aX, const shortx8* bX, int i0) {
    __builtin_amdgcn_s_setprio(1);
#pragma unroll
    for (int ii = 0; ii < 2; ++ii)
#pragma unroll
      for (int j = 0; j < 4; ++j)
        acc[i0 + ii][j] = __builtin_amdgcn_mfma_f32_16x16x32_bf16(
            aX[ii], bX[j], acc[i0 + ii][j], 0, 0, 0);
    __builtin_amdgcn_s_setprio(0);
  };

  // Prologue: tile 0 fully staged + B(1) in flight.
  stage_half(Ab, As, 0, 0, 0);
  stage_half(Ab, As, 0, 1, 0);
  stage_half(Bb, Bs, 0, 0, 0);
  stage_half(Bb, Bs, 0, 1, 0);
  stage_half(Bb, Bs, 1, 0, 64);
  stage_half(Bb, Bs, 1, 1, 64);
  WAITCNT_VM(4);  // tile 0 done, B(1)'s 4 loads stay in flight
  bar();

  const int NTILE = KDIM / 64;  // 32
#pragma unroll 2
  for (int T = 0; T < NTILE; ++T) {
    int d = T & 1, d1 = d ^ 1;
    const __hip_bfloat16* Asd = As + d * 16384;
    const __hip_bfloat16* Bsd = Bs + d * 16384;
    int kn = (T + 1) * 64;

    shortx8 aU[2], aV[2], b0[4], b1[4];
    // t0
    ldb4(b0, Bsd, 0);
    lda2(aU, Asd, 0, 0);
    if (T + 1 < NTILE) {
      stage_half(Ab, As, d1, 0, kn);
      stage_half(Ab, As, d1, 1, kn);
    }
    lda2(aV, Asd, 2, 0);
    mma8(aU, b0, 0);
    // t1
    lda2(aU, Asd, 4, 0);
    mma8(aV, b0, 2);
    // t2
    lda2(aV, Asd, 6, 0);
    ldb4(b1, Bsd, 1);
    mma8(aU, b0, 4);
    // t3
    lda2(aU, Asd, 0, 1);
    mma8(aV, b0, 6);
    // t4
    lda2(aV, Asd, 2, 1);
    mma8(aU, b1, 0);
    bar();  // all waves' B(T) reads consumed -> B(T+2) stage safe
    // t5
    if (T + 2 < NTILE) stage_half(Bb, Bs, d, 0, kn + 64);
    lda2(aU, Asd, 4, 1);
    mma8(aV, b1, 2);
    // t6
    if (T + 2 < NTILE) stage_half(Bb, Bs, d, 1, kn + 64);
    lda2(aV, Asd, 6, 1);
    mma8(aU, b1, 4);
    // t7
    mma8(aV, b1, 6);
    if (T + 2 < NTILE) {
      WAITCNT_VM(4);  // tile T+1 complete; B(T+2)'s 4 loads in flight
    } else if (T + 1 < NTILE) {
      WAITCNT_VM(0);  // tail drain (no prefetch outstanding after)
    }
    bar();
  }

  // Epilogue: highway gate fuse.
  int crow0 = bn * 256 + wr * 128 + q * 4;
  int ccol0 = bm * 256 + wc * 64 + frow;
#pragma unroll
  for (int i = 0; i < 8; ++i)
#pragma unroll
    for (int j = 0; j < 4; ++j) {
      int gcol = ccol0 + j * 16;
      float bb = (gcol & 1) ? hwb[2048 + (gcol >> 1)] : hwb[gcol >> 1];
#pragma unroll
      for (int r = 0; r < 4; ++r) {
        int row = crow0 + i * 16 + r;
        float v = acc[i][j][r] + bb;
        float partner = __shfl_xor(v, 1);
        if (!(lane & 1)) {  // even lane holds nl, partner is gate pre-act
          float gte = 1.f / (1.f + expf(-partner));
          int ch = gcol >> 1;
          float hold = __bfloat162float(A[(size_t)row * 2048 + ch]);
          float hnew = gte * hold + (1.f - gte) * fmaxf(v, 0.f);
          Hdst[(size_t)row * 2048 + ch] = __float2bfloat16(hnew);
        }
      }
    }
}

// ---------------------------------------------------------------------------
// Projection GEMM: 32x128 tile (grid 4x128 = 512 blocks, 2/CU), BK=64,
// same XOR swizzle. C fp32 + bias.
// ---------------------------------------------------------------------------
__global__ __launch_bounds__(256) void gemm_proj(
    const __hip_bfloat16* __restrict__ A, const __hip_bfloat16* __restrict__ B,
    float* __restrict__ C, const float* __restrict__ bias) {
  const int K = KDIM;
  __shared__ __align__(16) __hip_bfloat16 As[32 * 64];
  __shared__ __align__(16) __hip_bfloat16 Bs[128 * 64];
  int tid = threadIdx.x;
  int wave = tid >> 6, lane = tid & 63;
  int wr = wave >> 1, wc = wave & 1;
  int bn = blockIdx.y, bm = blockIdx.x;

  int sr8 = lane >> 3, sc8 = lane & 7;
  int frow = lane & 15, q = lane >> 4;

  floatx4 acc[4];
  floatx4 zero = {0.f, 0.f, 0.f, 0.f};
#pragma unroll
  for (int j = 0; j < 4; ++j) acc[j] = zero;

  const __hip_bfloat16* Ab = A + (size_t)bn * 32 * K;
  const __hip_bfloat16* Bb = B + (size_t)bm * 128 * K;

  for (int kb = 0; kb < K; kb += 64) {
    __syncthreads();
    {
      int r = wave * 8 + sr8;
      int gc = sc8 ^ (r & 7);
      async_copy16(Ab + (size_t)r * K + kb + gc * 8, (char*)As + wave * 1024);
    }
#pragma unroll
    for (int it = 0; it < 4; ++it) {
      int seg = wave * 4 + it;
      int r = seg * 8 + sr8;
      int gc = sc8 ^ (r & 7);
      async_copy16(Bb + (size_t)r * K + kb + gc * 8, (char*)Bs + seg * 1024);
    }
    __syncthreads();

#pragma unroll
    for (int s = 0; s < 2; ++s) {
      shortx8 af, bf[4];
      {
        int r = wr * 16 + frow;
        af = *(const shortx8*)(As + r * 64 + ((s * 4 + q) ^ (r & 7)) * 8);
      }
#pragma unroll
      for (int j = 0; j < 4; ++j) {
        int r = wc * 64 + j * 16 + frow;
        bf[j] = *(const shortx8*)(Bs + r * 64 + ((s * 4 + q) ^ (r & 7)) * 8);
      }
#pragma unroll
      for (int j = 0; j < 4; ++j)
        acc[j] = __builtin_amdgcn_mfma_f32_16x16x32_bf16(af, bf[j], acc[j],
                                                          0, 0, 0);
    }
  }

  int crow0 = bn * 32 + wr * 16 + q * 4;
  int ccol0 = bm * 128 + wc * 64 + frow;
#pragma unroll
  for (int j = 0; j < 4; ++j) {
    int c = ccol0 + j * 16;
#pragma unroll
    for (int r = 0; r < 4; ++r) {
      int row = crow0 + r;
      C[(size_t)row * PDIM + c] = acc[j][r] + bias[c];
    }
  }
}

// ---------------------------------------------------------------------------
extern "C" void kernel_launch(void* const* d_in, const int* in_sizes, int n_in,
                              void* d_out, int out_size, void* d_ws, size_t ws_size,
                              hipStream_t stream) {
  const int*   chars  = (const int*)d_in[1];
  const float* emb    = (const float*)d_in[2];
  const float* cw[7];
  const float* cb[7];
  for (int i = 0; i < 7; ++i) {
    cw[i] = (const float*)d_in[3 + 2 * i];
    cb[i] = (const float*)d_in[4 + 2 * i];
  }
  const float* hw_w0  = (const float*)d_in[17];
  const float* hw_b0  = (const float*)d_in[18];
  const float* hw_w1  = (const float*)d_in[19];
  const float* hw_b1  = (const float*)d_in[20];
  const float* proj_w = (const float*)d_in[21];
  const float* proj_b = (const float*)d_in[22];
  float* out = (float*)d_out;

  // Workspace (82 MiB):
  //   [0,16)   h   bf16 4096x2048      [16,32) h2  bf16 4096x2048
  //   [32,36)  convWb 512KB + convBc 8KB + embb 8.4KB
  //   [36,46)  Xg bf16 4096x72x16 (9 MB)
  //   [48,64)  w0b  [64,80) w1b  [80,82) pwb
  char* ws = (char*)d_ws;
  __hip_bfloat16* h      = (__hip_bfloat16*)(ws);
  __hip_bfloat16* h2     = (__hip_bfloat16*)(ws + (16ull << 20));
  __hip_bfloat16* convWb = (__hip_bfloat16*)(ws + (32ull << 20));
  float*          convBc = (float*)(ws + (32ull << 20) + 524288);
  __hip_bfloat16* embb   = (__hip_bfloat16*)(ws + (32ull << 20) + 524288 + 8192);
  __hip_bfloat16* Xg     = (__hip_bfloat16*)(ws + (36ull << 20));
  __hip_bfloat16* w0b    = (__hip_bfloat16*)(ws + (48ull << 20));
  __hip_bfloat16* w1b    = (__hip_bfloat16*)(ws + (64ull << 20));
  __hip_bfloat16* pwb    = (__hip_bfloat16*)(ws + (80ull << 20));

  // R10 order: cvts first, then prep (+xprep), then conv, then GEMMs.
  cvt_hw8<<<(HID * KDIM / 8) / 256, 256, 0, stream>>>(hw_w0, w0b);
  cvt_hw8<<<(HID * KDIM / 8) / 256, 256, 0, stream>>>(hw_w1, w1b);
  cvt8_kernel<<<(PDIM * KDIM / 8) / 256, 256, 0, stream>>>(proj_w, pwb,
                                                           PDIM * KDIM / 8);
  conv_wprep<<<(262144 + 2048 + 4192 + 255) / 256, 256, 0, stream>>>(
      cw[0], cw[1], cw[2], cw[3], cw[4], cw[5], cw[6],
      cb[0], cb[1], cb[2], cb[3], cb[4], cb[5], cb[6], emb,
      convWb, convBc, embb);
  conv_xprep<<<(NTOK * 72 + 255) / 256, 256, 0, stream>>>(chars, embb, Xg);

  // Conv: single launch, A-fragments straight from Xg.
  conv_all<<<dim3(128, 32), 256, 0, stream>>>(Xg, convWb, convBc, h);

  // 256^2-tile deep-pipelined highway GEMMs: grid 256 (1 block/CU), 512 thr.
  gemm_hw8<<<dim3(256), 512, 0, stream>>>(h, w0b, hw_b0, h2);
  gemm_hw8<<<dim3(256), 512, 0, stream>>>(h2, w1b, hw_b1, h);
  gemm_proj<<<dim3(PDIM / 128, NTOK / 32), 256, 0, stream>>>(h, pwb, out,
                                                             proj_b);
}

// Round 9
// 435.771 us; speedup vs baseline: 1.1846x; 1.0074x over previous
//
#include <hip/hip_runtime.h>
#include <hip/hip_bf16.h>

// ---------------------------------------------------------------------------
// ConvTokenEmbedder: char-CNN -> 2x highway -> projection
// R16 = R15 with conv_all's epilogue VALU cut (the measured co-bottleneck:
//     VALUBusy 44% vs MfmaUtil 35%):
//     1) g-invariant mask addend madd[j][r] in {0,-2e30} precomputed once;
//        masked tail-block max = 1 v_add instead of cmp+max+cndmask.
//        (Masking only ever applies to the LAST t-row block: Tv>=44>32.)
//     2) balanced fmax trees (v_max3_f32 fusion) replace 11-deep serial
//        chains: ~25 -> ~14 VALU per j-fragment.
//     All other kernels byte-identical to R15 (gemm = R10-proven form).
// ---------------------------------------------------------------------------

#define NTOK 4096
#define NF   2048
#define KDIM 2048
#define HID  4096
#define PDIM 512

typedef __attribute__((ext_vector_type(4))) float floatx4;
typedef __attribute__((ext_vector_type(8))) short shortx8;

__device__ inline void async_copy16(const void* g, void* l) {
  __builtin_amdgcn_global_load_lds(
      (const __attribute__((address_space(1))) void*)(uintptr_t)g,
      (__attribute__((address_space(3))) void*)(uint32_t)(uintptr_t)l,
      16, 0, 0);
}

__device__ inline void bar() {
  __builtin_amdgcn_sched_barrier(0);
  __builtin_amdgcn_s_barrier();
  __builtin_amdgcn_sched_barrier(0);
}

#define WAITCNT_VM(N)                                  \
  do {                                                 \
    __builtin_amdgcn_sched_barrier(0);                 \
    asm volatile("s_waitcnt vmcnt(" #N ")");           \
    __builtin_amdgcn_sched_barrier(0);                 \
  } while (0)

// ---------------------------------------------------------------------------
// Vectorized fp32 -> bf16 (8 elems/thread).
__global__ __launch_bounds__(256) void cvt8_kernel(
    const float* __restrict__ s, __hip_bfloat16* __restrict__ d, int n8) {
  int i = blockIdx.x * 256 + threadIdx.x;
  if (i < n8) {
    floatx4 v0 = *(const floatx4*)(s + (size_t)i * 8);
    floatx4 v1 = *(const floatx4*)(s + (size_t)i * 8 + 4);
    union { shortx8 v; __hip_bfloat16 h[8]; } u;
#pragma unroll
    for (int t = 0; t < 4; ++t) u.h[t] = __float2bfloat16(v0[t]);
#pragma unroll
    for (int t = 0; t < 4; ++t) u.h[4 + t] = __float2bfloat16(v1[t]);
    *(shortx8*)(d + (size_t)i * 8) = u.v;
  }
}

// Highway weight cvt with nl/gate row interleave: dst row r = src row
// (r>>1) + (r&1)*2048. So cols 2j/2j+1 of p' are (nl_j, gate_j).
__global__ __launch_bounds__(256) void cvt_hw8(
    const float* __restrict__ s, __hip_bfloat16* __restrict__ d) {
  int i = blockIdx.x * 256 + threadIdx.x;  // over 4096*2048/8
  int r = i >> 8;             // 256 threads per 2048-wide row
  int kb = (i & 255) * 8;
  int sr = (r >> 1) + (r & 1) * 2048;
  const float* src = s + (size_t)sr * 2048 + kb;
  floatx4 v0 = *(const floatx4*)(src);
  floatx4 v1 = *(const floatx4*)(src + 4);
  union { shortx8 v; __hip_bfloat16 h[8]; } u;
#pragma unroll
  for (int t = 0; t < 4; ++t) u.h[t] = __float2bfloat16(v0[t]);
#pragma unroll
  for (int t = 0; t < 4; ++t) u.h[4 + t] = __float2bfloat16(v1[t]);
  *(shortx8*)(d + (size_t)r * 2048 + kb) = u.v;
}

// ---------------------------------------------------------------------------
// Conv weight prep: Wb[ch][kp], kp = k*16+d, K padded to 128 (zeros k>=w).
// Plus bias pack [2048] and bf16 emb table [262*16].
// ---------------------------------------------------------------------------
__global__ __launch_bounds__(256) void conv_wprep(
    const float* __restrict__ w0, const float* __restrict__ w1,
    const float* __restrict__ w2, const float* __restrict__ w3,
    const float* __restrict__ w4, const float* __restrict__ w5,
    const float* __restrict__ w6,
    const float* __restrict__ b0, const float* __restrict__ b1,
    const float* __restrict__ b2, const float* __restrict__ b3,
    const float* __restrict__ b4, const float* __restrict__ b5,
    const float* __restrict__ b6, const float* __restrict__ emb,
    __hip_bfloat16* __restrict__ Wb, float* __restrict__ Bc,
    __hip_bfloat16* __restrict__ embb) {
  int idx = blockIdx.x * 256 + threadIdx.x;
  const int start[7] = {0, 32, 64, 128, 256, 512, 1024};
  const float* ws[7] = {w0, w1, w2, w3, w4, w5, w6};
  const float* bs[7] = {b0, b1, b2, b3, b4, b5, b6};
  if (idx < 262144) {
    int ch = idx >> 7, kp = idx & 127;
    int f = (ch >= 32) + (ch >= 64) + (ch >= 128) + (ch >= 256) +
            (ch >= 512) + (ch >= 1024);
    int w = f + 1, lc = ch - start[f];
    int d = kp & 15, k = kp >> 4;
    float v = (k < w) ? ws[f][((size_t)lc * 16 + d) * w + k] : 0.f;
    Wb[idx] = __float2bfloat16(v);
  } else if (idx < 262144 + 2048) {
    int ch = idx - 262144;
    int f = (ch >= 32) + (ch >= 64) + (ch >= 128) + (ch >= 256) +
            (ch >= 512) + (ch >= 1024);
    Bc[ch] = bs[f][ch - start[f]];
  } else if (idx < 262144 + 2048 + 4192) {
    int e = idx - 262144 - 2048;
    embb[e] = __float2bfloat16(emb[e]);
  }
}

// ---------------------------------------------------------------------------
// im2col pre-materialization: Xg[tok][r][d], r in [0,72), rows >= 50 zero.
// ---------------------------------------------------------------------------
__global__ __launch_bounds__(256) void conv_xprep(
    const int* __restrict__ chars, const __hip_bfloat16* __restrict__ embb,
    __hip_bfloat16* __restrict__ Xg) {
  int idx = blockIdx.x * 256 + threadIdx.x;  // over 4096*72
  if (idx >= NTOK * 72) return;
  int tok = idx / 72, r = idx - tok * 72;
  shortx8 v0 = {0, 0, 0, 0, 0, 0, 0, 0};
  shortx8 v1 = {0, 0, 0, 0, 0, 0, 0, 0};
  if (r < 50) {
    int c = chars[(size_t)tok * 50 + r];
    const shortx8* e = (const shortx8*)(embb + c * 16);
    v0 = e[0];
    v1 = e[1];
  }
  *(shortx8*)(Xg + (size_t)idx * 16) = v0;
  *(shortx8*)(Xg + (size_t)idx * 16 + 8) = v1;
}

// ---------------------------------------------------------------------------
// Conv: A-fragments loaded straight from Xg at constant offsets.
// Each wave: 64 channels x 8 tokens. W register-resident. No LDS/barriers.
// Epilogue: g-invariant mask addend + balanced max3 trees (R16).
// ---------------------------------------------------------------------------
template <int NKT, int NT>
__device__ __forceinline__ void conv_body(
    const __hip_bfloat16* __restrict__ Xg,
    const __hip_bfloat16* __restrict__ Wb, const float* __restrict__ bias,
    __hip_bfloat16* __restrict__ h, int chb, int tokbase) {
  int tid = threadIdx.x, wave = tid >> 6, lane = tid & 63;
  int frow = lane & 15, q = lane >> 4;

  shortx8 wreg[NKT][4];
#pragma unroll
  for (int kt = 0; kt < NKT; ++kt)
#pragma unroll
    for (int j = 0; j < 4; ++j)
      wreg[kt][j] = *(const shortx8*)(
          Wb + (size_t)(chb + j * 16 + frow) * 128 + kt * 32 + q * 8);

  float blane = bias[chb + lane];

  // Mask addend for the LAST t-row block only (Tv >= 44 > 32 guarantees all
  // earlier blocks valid). madd = 0 (keep) or -2e30 (drop; absorbs any
  // real acc magnitude <= ~1e3 exactly to -2e30 < all valid values).
  float madd[4][4];
#pragma unroll
  for (int j = 0; j < 4; ++j) {
    int ch = chb + j * 16 + frow;
    int w = 1 + (ch >= 32) + (ch >= 64) + (ch >= 128) + (ch >= 256) +
            (ch >= 512) + (ch >= 1024);
    int Tv = 51 - w;
#pragma unroll
    for (int r = 0; r < 4; ++r)
      madd[j][r] = ((NT - 1) * 16 + q * 4 + r < Tv) ? 0.f : -2e30f;
  }

  const floatx4 zero = {0.f, 0.f, 0.f, 0.f};
  int kkb = q >> 1, d0 = (q & 1) * 8;

#pragma unroll 1
  for (int g = 0; g < 8; ++g) {
    int tok = tokbase + g * 4 + wave;
    const __hip_bfloat16* Xt =
        Xg + ((size_t)tok * 72 + frow + kkb) * 16 + d0;

    floatx4 acc[NT][4];
#pragma unroll
    for (int kt = 0; kt < NKT; ++kt) {
      shortx8 xf[NT];
#pragma unroll
      for (int i = 0; i < NT; ++i)
        xf[i] = *(const shortx8*)(Xt + (size_t)(i * 16 + kt * 2) * 16);
#pragma unroll
      for (int i = 0; i < NT; ++i)
#pragma unroll
        for (int j = 0; j < 4; ++j) {
          if (kt == 0)
            acc[i][j] = __builtin_amdgcn_mfma_f32_16x16x32_bf16(
                xf[i], wreg[0][j], zero, 0, 0, 0);
          else
            acc[i][j] = __builtin_amdgcn_mfma_f32_16x16x32_bf16(
                xf[i], wreg[kt][j], acc[i][j], 0, 0, 0);
        }
    }

    float vj[4];
#pragma unroll
    for (int j = 0; j < 4; ++j) {
      float m0 = acc[NT - 1][j][0] + madd[j][0];
      float m1 = acc[NT - 1][j][1] + madd[j][1];
      float m2 = acc[NT - 1][j][2] + madd[j][2];
      float m3 = acc[NT - 1][j][3] + madd[j][3];
      float v;
      if (NT == 3) {
        float t0 = fmaxf(fmaxf(acc[0][j][0], acc[0][j][1]), acc[0][j][2]);
        float t1 = fmaxf(fmaxf(acc[0][j][3], acc[1][j][0]), acc[1][j][1]);
        float t2 = fmaxf(fmaxf(acc[1][j][2], acc[1][j][3]), m0);
        float t3 = fmaxf(fmaxf(m1, m2), m3);
        v = fmaxf(fmaxf(fmaxf(t0, t1), t2), t3);
      } else {  // NT == 4
        float t0 = fmaxf(fmaxf(acc[0][j][0], acc[0][j][1]), acc[0][j][2]);
        float t1 = fmaxf(fmaxf(acc[0][j][3], acc[1][j][0]), acc[1][j][1]);
        float t2 = fmaxf(fmaxf(acc[1][j][2], acc[1][j][3]), acc[2][j][0]);
        float t3 = fmaxf(fmaxf(acc[2][j][1], acc[2][j][2]), acc[2][j][3]);
        float t4 = fmaxf(fmaxf(m0, m1), m2);
        float u0 = fmaxf(fmaxf(t0, t1), t2);
        float u1 = fmaxf(fmaxf(t3, t4), m3);
        v = fmaxf(u0, u1);
      }
      v = fmaxf(v, __shfl_xor(v, 16));
      v = fmaxf(v, __shfl_xor(v, 32));
      vj[j] = v;
    }
    float r0 = (q & 2) ? vj[2] : vj[0];
    float r1 = (q & 2) ? vj[3] : vj[1];
    float rv = (q & 1) ? r1 : r0;
    h[(size_t)tok * NF + chb + lane] =
        __float2bfloat16(fmaxf(rv + blane, 0.f));
  }
}

__global__ __launch_bounds__(256) void conv_all(
    const __hip_bfloat16* __restrict__ Xg,
    const __hip_bfloat16* __restrict__ Wb, const float* __restrict__ bias,
    __hip_bfloat16* __restrict__ h) {
  int by = blockIdx.y;
  int chb = by * 64;
  int tokbase = blockIdx.x * 32;
  if (by == 0)
    conv_body<1, 4>(Xg, Wb, bias, h, chb, tokbase);
  else if (by < 4)
    conv_body<2, 3>(Xg, Wb, bias, h, chb, tokbase);
  else if (by < 16)
    conv_body<3, 3>(Xg, Wb, bias, h, chb, tokbase);
  else
    conv_body<4, 3>(Xg, Wb, bias, h, chb, tokbase);
}

// ---------------------------------------------------------------------------
// Highway-fused GEMM, 256x256 tile, deep-pipelined, 2 barriers per K-tile.
// Byte-identical to R10 (best measured: 88.5 us x5).
// ---------------------------------------------------------------------------
__global__ __launch_bounds__(512, 2) void gemm_hw8(
    const __hip_bfloat16* __restrict__ A, const __hip_bfloat16* __restrict__ B,
    const float* __restrict__ hwb, __hip_bfloat16* __restrict__ Hdst) {
  __shared__ __align__(16) __hip_bfloat16 As[2 * 256 * 64];
  __shared__ __align__(16) __hip_bfloat16 Bs[2 * 256 * 64];
  int tid = threadIdx.x;
  int wave = tid >> 6, lane = tid & 63;
  int wr = wave >> 2, wc = wave & 3;     // 2 x 4 wave grid
  int sr8 = lane >> 3, sc8 = lane & 7;   // staging row-in-seg / chunk slot
  int frow = lane & 15, q = lane >> 4;

  // Bijective 1D XCD swizzle (R10): XCD x gets bn {2x,2x+1}.
  int wg = blockIdx.x;
  int swz = (wg & 7) * 32 + (wg >> 3);
  int bm = swz & 15;   // w tile (N dim)
  int bn = swz >> 4;   // token tile (M dim)

  const __hip_bfloat16* Ab = A + (size_t)bn * 256 * KDIM;
  const __hip_bfloat16* Bb = B + (size_t)bm * 256 * KDIM;

  floatx4 acc[8][4];
  const floatx4 zero = {0.f, 0.f, 0.f, 0.f};
#pragma unroll
  for (int i = 0; i < 8; ++i)
#pragma unroll
    for (int j = 0; j < 4; ++j) acc[i][j] = zero;

  auto stage_half = [&](const __hip_bfloat16* gsrc, __hip_bfloat16* lbase,
                        int d, int hf, int kb) {
#pragma unroll
    for (int it = 0; it < 2; ++it) {
      int row = hf * 128 + (wave * 2 + it) * 8;  // segment start row (uniform)
      int r = row + sr8;
      int gc = sc8 ^ sr8;
      async_copy16(gsrc + (size_t)r * KDIM + kb + gc * 8,
                   (char*)lbase + ((size_t)d * 256 + row) * 128);
    }
  };

  auto lda2 = [&](shortx8* dst2, const __hip_bfloat16* Asd, int i0, int s) {
#pragma unroll
    for (int ii = 0; ii < 2; ++ii) {
      int r = wr * 128 + (i0 + ii) * 16 + frow;
      dst2[ii] = *(const shortx8*)(Asd + r * 64 +
                                   (((s * 4 + q) ^ (frow & 7)) << 3));
    }
  };
  auto ldb4 = [&](shortx8* dst4, const __hip_bfloat16* Bsd, int s) {
#pragma unroll
    for (int j = 0; j < 4; ++j) {
      int r = wc * 64 + j * 16 + frow;
      dst4[j] = *(const shortx8*)(Bsd + r * 64 +
                                  (((s * 4 + q) ^ (frow & 7)) << 3));
    }
  };
  auto mma8 = [&](const shortx8* aX, const shortx8* bX, int i0) {
    __builtin_amdgcn_s_setprio(1);
#pragma unroll
    for (int ii = 0; ii < 2; ++ii)
#pragma unroll
      for (int j = 0; j < 4; ++j)
        acc[i0 + ii][j] = __builtin_amdgcn_mfma_f32_16x16x32_bf16(
            aX[ii], bX[j], acc[i0 + ii][j], 0, 0, 0);
    __builtin_amdgcn_s_setprio(0);
  };

  // Prologue: tile 0 fully staged + B(1) in flight.
  stage_half(Ab, As, 0, 0, 0);
  stage_half(Ab, As, 0, 1, 0);
  stage_half(Bb, Bs, 0, 0, 0);
  stage_half(Bb, Bs, 0, 1, 0);
  stage_half(Bb, Bs, 1, 0, 64);
  stage_half(Bb, Bs, 1, 1, 64);
  WAITCNT_VM(4);  // tile 0 done, B(1)'s 4 loads stay in flight
  bar();

  const int NTILE = KDIM / 64;  // 32
#pragma unroll 2
  for (int T = 0; T < NTILE; ++T) {
    int d = T & 1, d1 = d ^ 1;
    const __hip_bfloat16* Asd = As + d * 16384;
    const __hip_bfloat16* Bsd = Bs + d * 16384;
    int kn = (T + 1) * 64;

    shortx8 aU[2], aV[2], b0[4], b1[4];
    // t0
    ldb4(b0, Bsd, 0);
    lda2(aU, Asd, 0, 0);
    if (T + 1 < NTILE) {
      stage_half(Ab, As, d1, 0, kn);
      stage_half(Ab, As, d1, 1, kn);
    }
    lda2(aV, Asd, 2, 0);
    mma8(aU, b0, 0);
    // t1
    lda2(aU, Asd, 4, 0);
    mma8(aV, b0, 2);
    // t2
    lda2(aV, Asd, 6, 0);
    ldb4(b1, Bsd, 1);
    mma8(aU, b0, 4);
    // t3
    lda2(aU, Asd, 0, 1);
    mma8(aV, b0, 6);
    // t4
    lda2(aV, Asd, 2, 1);
    mma8(aU, b1, 0);
    bar();  // all waves' B(T) reads consumed -> B(T+2) stage safe
    // t5
    if (T + 2 < NTILE) stage_half(Bb, Bs, d, 0, kn + 64);
    lda2(aU, Asd, 4, 1);
    mma8(aV, b1, 2);
    // t6
    if (T + 2 < NTILE) stage_half(Bb, Bs, d, 1, kn + 64);
    lda2(aV, Asd, 6, 1);
    mma8(aU, b1, 4);
    // t7
    mma8(aV, b1, 6);
    if (T + 2 < NTILE) {
      WAITCNT_VM(4);  // tile T+1 complete; B(T+2)'s 4 loads in flight
    } else if (T + 1 < NTILE) {
      WAITCNT_VM(0);  // tail drain (no prefetch outstanding after)
    }
    bar();
  }

  // Epilogue: highway gate fuse.
  int crow0 = bn * 256 + wr * 128 + q * 4;
  int ccol0 = bm * 256 + wc * 64 + frow;
#pragma unroll
  for (int i = 0; i < 8; ++i)
#pragma unroll
    for (int j = 0; j < 4; ++j) {
      int gcol = ccol0 + j * 16;
      float bb = (gcol & 1) ? hwb[2048 + (gcol >> 1)] : hwb[gcol >> 1];
#pragma unroll
      for (int r = 0; r < 4; ++r) {
        int row = crow0 + i * 16 + r;
        float v = acc[i][j][r] + bb;
        float partner = __shfl_xor(v, 1);
        if (!(lane & 1)) {  // even lane holds nl, partner is gate pre-act
          float gte = 1.f / (1.f + expf(-partner));
          int ch = gcol >> 1;
          float hold = __bfloat162float(A[(size_t)row * 2048 + ch]);
          float hnew = gte * hold + (1.f - gte) * fmaxf(v, 0.f);
          Hdst[(size_t)row * 2048 + ch] = __float2bfloat16(hnew);
        }
      }
    }
}

// ---------------------------------------------------------------------------
// Projection GEMM: 32x128 tile (grid 4x128 = 512 blocks, 2/CU), BK=64,
// same XOR swizzle. C fp32 + bias.
// ---------------------------------------------------------------------------
__global__ __launch_bounds__(256) void gemm_proj(
    const __hip_bfloat16* __restrict__ A, const __hip_bfloat16* __restrict__ B,
    float* __restrict__ C, const float* __restrict__ bias) {
  const int K = KDIM;
  __shared__ __align__(16) __hip_bfloat16 As[32 * 64];
  __shared__ __align__(16) __hip_bfloat16 Bs[128 * 64];
  int tid = threadIdx.x;
  int wave = tid >> 6, lane = tid & 63;
  int wr = wave >> 1, wc = wave & 1;
  int bn = blockIdx.y, bm = blockIdx.x;

  int sr8 = lane >> 3, sc8 = lane & 7;
  int frow = lane & 15, q = lane >> 4;

  floatx4 acc[4];
  floatx4 zero = {0.f, 0.f, 0.f, 0.f};
#pragma unroll
  for (int j = 0; j < 4; ++j) acc[j] = zero;

  const __hip_bfloat16* Ab = A + (size_t)bn * 32 * K;
  const __hip_bfloat16* Bb = B + (size_t)bm * 128 * K;

  for (int kb = 0; kb < K; kb += 64) {
    __syncthreads();
    {
      int r = wave * 8 + sr8;
      int gc = sc8 ^ (r & 7);
      async_copy16(Ab + (size_t)r * K + kb + gc * 8, (char*)As + wave * 1024);
    }
#pragma unroll
    for (int it = 0; it < 4; ++it) {
      int seg = wave * 4 + it;
      int r = seg * 8 + sr8;
      int gc = sc8 ^ (r & 7);
      async_copy16(Bb + (size_t)r * K + kb + gc * 8, (char*)Bs + seg * 1024);
    }
    __syncthreads();

#pragma unroll
    for (int s = 0; s < 2; ++s) {
      shortx8 af, bf[4];
      {
        int r = wr * 16 + frow;
        af = *(const shortx8*)(As + r * 64 + ((s * 4 + q) ^ (r & 7)) * 8);
      }
#pragma unroll
      for (int j = 0; j < 4; ++j) {
        int r = wc * 64 + j * 16 + frow;
        bf[j] = *(const shortx8*)(Bs + r * 64 + ((s * 4 + q) ^ (r & 7)) * 8);
      }
#pragma unroll
      for (int j = 0; j < 4; ++j)
        acc[j] = __builtin_amdgcn_mfma_f32_16x16x32_bf16(af, bf[j], acc[j],
                                                          0, 0, 0);
    }
  }

  int crow0 = bn * 32 + wr * 16 + q * 4;
  int ccol0 = bm * 128 + wc * 64 + frow;
#pragma unroll
  for (int j = 0; j < 4; ++j) {
    int c = ccol0 + j * 16;
#pragma unroll
    for (int r = 0; r < 4; ++r) {
      int row = crow0 + r;
      C[(size_t)row * PDIM + c] = acc[j][r] + bias[c];
    }
  }
}

// ---------------------------------------------------------------------------
extern "C" void kernel_launch(void* const* d_in, const int* in_sizes, int n_in,
                              void* d_out, int out_size, void* d_ws, size_t ws_size,
                              hipStream_t stream) {
  const int*   chars  = (const int*)d_in[1];
  const float* emb    = (const float*)d_in[2];
  const float* cw[7];
  const float* cb[7];
  for (int i = 0; i < 7; ++i) {
    cw[i] = (const float*)d_in[3 + 2 * i];
    cb[i] = (const float*)d_in[4 + 2 * i];
  }
  const float* hw_w0  = (const float*)d_in[17];
  const float* hw_b0  = (const float*)d_in[18];
  const float* hw_w1  = (const float*)d_in[19];
  const float* hw_b1  = (const float*)d_in[20];
  const float* proj_w = (const float*)d_in[21];
  const float* proj_b = (const float*)d_in[22];
  float* out = (float*)d_out;

  // Workspace (82 MiB):
  //   [0,16)   h   bf16 4096x2048      [16,32) h2  bf16 4096x2048
  //   [32,36)  convWb 512KB + convBc 8KB + embb 8.4KB
  //   [36,46)  Xg bf16 4096x72x16 (9 MB)
  //   [48,64)  w0b  [64,80) w1b  [80,82) pwb
  char* ws = (char*)d_ws;
  __hip_bfloat16* h      = (__hip_bfloat16*)(ws);
  __hip_bfloat16* h2     = (__hip_bfloat16*)(ws + (16ull << 20));
  __hip_bfloat16* convWb = (__hip_bfloat16*)(ws + (32ull << 20));
  float*          convBc = (float*)(ws + (32ull << 20) + 524288);
  __hip_bfloat16* embb   = (__hip_bfloat16*)(ws + (32ull << 20) + 524288 + 8192);
  __hip_bfloat16* Xg     = (__hip_bfloat16*)(ws + (36ull << 20));
  __hip_bfloat16* w0b    = (__hip_bfloat16*)(ws + (48ull << 20));
  __hip_bfloat16* w1b    = (__hip_bfloat16*)(ws + (64ull << 20));
  __hip_bfloat16* pwb    = (__hip_bfloat16*)(ws + (80ull << 20));

  // R10 order: cvts first, then prep (+xprep), then conv, then GEMMs.
  cvt_hw8<<<(HID * KDIM / 8) / 256, 256, 0, stream>>>(hw_w0, w0b);
  cvt_hw8<<<(HID * KDIM / 8) / 256, 256, 0, stream>>>(hw_w1, w1b);
  cvt8_kernel<<<(PDIM * KDIM / 8) / 256, 256, 0, stream>>>(proj_w, pwb,
                                                           PDIM * KDIM / 8);
  conv_wprep<<<(262144 + 2048 + 4192 + 255) / 256, 256, 0, stream>>>(
      cw[0], cw[1], cw[2], cw[3], cw[4], cw[5], cw[6],
      cb[0], cb[1], cb[2], cb[3], cb[4], cb[5], cb[6], emb,
      convWb, convBc, embb);
  conv_xprep<<<(NTOK * 72 + 255) / 256, 256, 0, stream>>>(chars, embb, Xg);

  // Conv: single launch, A-fragments straight from Xg.
  conv_all<<<dim3(128, 32), 256, 0, stream>>>(Xg, convWb, convBc, h);

  // 256^2-tile deep-pipelined highway GEMMs: grid 256 (1 block/CU), 512 thr.
  gemm_hw8<<<dim3(256), 512, 0, stream>>>(h, w0b, hw_b0, h2);
  gemm_hw8<<<dim3(256), 512, 0, stream>>>(h2, w1b, hw_b1, h);
  gemm_proj<<<dim3(PDIM / 128, NTOK / 32), 256, 0, stream>>>(h, pwb, out,
                                                             proj_b);
}